// Round 21
// baseline (925.103 us; speedup 1.0000x reference)
//
#include <hip/hip_runtime.h>
#include <cstdint>
#include <cstddef>

#define DEVI __device__ __forceinline__

static constexpr int HW = 65536;          // 256*256
static constexpr float PTOTF = 524288.0f; // 8*256*256
static constexpr int NPB = 8192;          // partial-stats stride (max blocks)

typedef __attribute__((ext_vector_type(8))) short bfx8;
typedef __attribute__((ext_vector_type(16))) float fx16;
typedef __attribute__((ext_vector_type(4))) float fx4;

DEVI unsigned short f2bf(float f) {
  unsigned int x = __float_as_uint(f);
  x += 0x7fffu + ((x >> 16) & 1u);
  return (unsigned short)(x >> 16);
}
DEVI float celuf(float v) { return v > 0.0f ? v : expm1f(v); }

DEVI void unpack8(const uint4 u, float* v) {
  v[0] = __uint_as_float(u.x << 16); v[1] = __uint_as_float(u.x & 0xffff0000u);
  v[2] = __uint_as_float(u.y << 16); v[3] = __uint_as_float(u.y & 0xffff0000u);
  v[4] = __uint_as_float(u.z << 16); v[5] = __uint_as_float(u.z & 0xffff0000u);
  v[6] = __uint_as_float(u.w << 16); v[7] = __uint_as_float(u.w & 0xffff0000u);
}

// async 16B global->LDS (linear LDS dest = uniform base + lane*16)
DEVI void gload16(const unsigned short* g, unsigned short* l) {
  __builtin_amdgcn_global_load_lds(
      (const __attribute__((address_space(1))) unsigned int*)g,
      (__attribute__((address_space(3))) unsigned int*)l, 16, 0, 0);
}

// padded pixel base index: interior (n,h,w) -> element offset/64
DEVI size_t padpx(int n, int h, int w) {
  return ((size_t)n * 258 + (h + 1)) * 258 + (w + 1);
}

// ---- merged prep: pad-zero borders + weight transforms
// wtm: LINEAR [cv][9 taps][64 oc][64 ic] bf16 (consumed via registers now).
// wc1: conv1 A-frag table [5 kchunks][2 oc-halves][64 lanes][8].
// wlast: bf16 A-fragment table [18 chunks][64 lanes][8] for mfma 16x16x32.
__global__ __launch_bounds__(256)
void k_prep(const float* __restrict__ w1, const float* __restrict__ bw,
            const float* __restrict__ w2, unsigned short* __restrict__ wc1,
            unsigned short* __restrict__ wtm, unsigned short* __restrict__ wlast,
            unsigned short* a, unsigned short* b, unsigned short* c) {
  int id = blockIdx.x * 256 + threadIdx.x;
  if (id < 24672) {  // pad-zero: 3 bufs x 8 n x 1028 border px
    const int buf = id / 8224, r = id - buf * 8224;
    const int n = r / 1028, k = r - n * 1028;
    int hp, wp;
    if (k < 258)      { hp = 0;           wp = k; }
    else if (k < 516) { hp = 257;         wp = k - 258; }
    else if (k < 772) { hp = k - 516 + 1; wp = 0; }
    else              { hp = k - 772 + 1; wp = 257; }
    unsigned short* p = (buf == 0 ? a : buf == 1 ? b : c) +
                        (((size_t)n * 258 + hp) * 258 + wp) * 64;
    const uint4 z = {0, 0, 0, 0};
#pragma unroll
    for (int q = 0; q < 8; ++q) ((uint4*)p)[q] = z;
    return;
  }
  id -= 24672;
  if (id < 221184) {  // wtm: bw [6][64][64][3][3] f32 -> [6][9][64][64] bf16
    const int cv = id / 36864, r = id - cv * 36864;
    const int tap = r >> 12, rr = r & 4095, oc = rr >> 6, ic = rr & 63;
    const float v = bw[((size_t)cv * 4096 + oc * 64 + ic) * 9 + tap];
    wtm[(size_t)cv * 36864 + tap * 4096 + oc * 64 + ic] = f2bf(v);
    return;
  }
  id -= 221184;
  if (id < 5120) {  // wc1 table
    const int cch = id >> 10, rr = id & 1023;
    const int m = rr >> 9, l = (rr >> 3) & 63, j = rr & 7;
    const int oc = m * 32 + (l & 31);
    const int tap = 2 * cch + (l >> 5);
    wc1[id] = (tap < 9 && j < 6) ? f2bf(w1[(oc * 6 + j) * 9 + tap])
                                 : (unsigned short)0;
    return;
  }
  id -= 5120;
  if (id < 9216) {  // wlast bf16 table
    const int cch = id >> 9, r = id & 511, l = r >> 3, j = r & 7;
    const int oc = l & 15, kg = l >> 4;
    const int tap = cch >> 1, kc = cch & 1;
    const int ic = kc * 32 + kg * 8 + j;
    wlast[id] = (oc < 3) ? f2bf(w2[(oc * 64 + ic) * 9 + tap]) : (unsigned short)0;
  }
}

// ---- instance norm stats: one block per (n,c)
__global__ __launch_bounds__(256)
void k_inorm(const float* __restrict__ x, float* __restrict__ ms) {
  __shared__ float s1[256], s2[256];
  const int b = blockIdx.x;
  const float4* p = (const float4*)(x + (size_t)b * HW);
  float sum = 0.f, sq = 0.f;
  for (int j = threadIdx.x; j < HW / 4; j += 256) {
    const float4 v = p[j];
    sum += v.x + v.y + v.z + v.w;
    sq  += v.x * v.x + v.y * v.y + v.z * v.z + v.w * v.w;
  }
  s1[threadIdx.x] = sum; s2[threadIdx.x] = sq;
  __syncthreads();
  for (int s = 128; s > 0; s >>= 1) {
    if ((int)threadIdx.x < s) {
      s1[threadIdx.x] += s1[threadIdx.x + s];
      s2[threadIdx.x] += s2[threadIdx.x + s];
    }
    __syncthreads();
  }
  if (threadIdx.x == 0) {
    const float m = s1[0] * (1.0f / HW);
    const float var = (s2[0] - s1[0] * s1[0] * (1.0f / HW)) * (1.0f / (HW - 1));
    ms[2 * b] = m;
    ms[2 * b + 1] = rsqrtf(var);
  }
}

// ---- conv1 (6->64) via MFMA (validated round 20): tile 4 rows x 64 px x 64 oc.
__global__ __launch_bounds__(256)
void k_conv1(const float* __restrict__ x, const float* __restrict__ ms,
             const unsigned short* __restrict__ wc1, unsigned short* __restrict__ out,
             float* __restrict__ psum, float* __restrict__ psq) {
  __shared__ __align__(16) unsigned short in_s[6 * 66 * 8];  // 6336 B
  __shared__ float s_red[2][4][64];

  const int t = threadIdx.x;
  const int lane = t & 63, wv = t >> 6;
  const int l31 = lane & 31, hi = lane >> 5;
  const int b = blockIdx.x;
  const int n = b >> 8;
  const int h0 = ((b >> 2) & 63) * 4;
  const int w0 = (b & 3) * 64;

  const float m0 = ms[6 * n + 0], r0 = ms[6 * n + 1];
  const float m1 = ms[6 * n + 2], r1 = ms[6 * n + 3];
  const float m2 = ms[6 * n + 4], r2 = ms[6 * n + 5];

  for (int id = t; id < 396; id += 256) {
    const int r = id / 66, px = id - r * 66;
    const int gh = h0 + r - 1, gw = w0 + px - 1;
    uint4 u = {0, 0, 0, 0};
    if (((unsigned)gh < 256u) && ((unsigned)gw < 256u)) {
      const float* xp = x + (size_t)n * 3 * HW + gh * 256 + gw;
      const float a0 = xp[0], a1 = xp[HW], a2 = xp[2 * HW];
      const float n0 = (a0 - m0) * r0, n1 = (a1 - m1) * r1, n2 = (a2 - m2) * r2;
      u.x = (unsigned)f2bf(a0) | ((unsigned)f2bf(a1) << 16);
      u.y = (unsigned)f2bf(a2) | ((unsigned)f2bf(n0) << 16);
      u.z = (unsigned)f2bf(n1) | ((unsigned)f2bf(n2) << 16);
    }
    *(uint4*)(in_s + (size_t)id * 8) = u;
  }
  __syncthreads();

  fx16 acc[2][2] = {};
#pragma unroll
  for (int c = 0; c < 5; ++c) {
    bfx8 af[2];
#pragma unroll
    for (int m = 0; m < 2; ++m)
      af[m] = *(const bfx8*)(wc1 + ((size_t)(c * 2 + m) * 64 + lane) * 8);
    const int tap = 2 * c + hi;
    const int dh = (tap < 9) ? tap / 3 : 0;
    const int dw = (tap < 9) ? (tap - (tap / 3) * 3) : 0;
    bfx8 bf[2];
#pragma unroll
    for (int p = 0; p < 2; ++p) {
      const int px = p * 32 + l31 + dw;
      bf[p] = *(const bfx8*)(in_s + ((size_t)(wv + dh) * 66 + px) * 8);
    }
#pragma unroll
    for (int m = 0; m < 2; ++m)
#pragma unroll
      for (int p = 0; p < 2; ++p)
        acc[m][p] = __builtin_amdgcn_mfma_f32_32x32x16_bf16(
            af[m], bf[p], acc[m][p], 0, 0, 0);
  }

  const size_t obase = (((size_t)n * 258 + (h0 + wv + 1)) * 258 + (w0 + 1)) * 64;
  float sv[2][16], qv[2][16];
#pragma unroll
  for (int m = 0; m < 2; ++m) {
#pragma unroll
    for (int p = 0; p < 2; ++p) {
      const int px = p * 32 + l31;
#pragma unroll
      for (int q = 0; q < 4; ++q) {
        const int ocb = m * 32 + q * 8 + 4 * hi;
        ushort4 o;
        o.x = f2bf(acc[m][p][q * 4 + 0]);
        o.y = f2bf(acc[m][p][q * 4 + 1]);
        o.z = f2bf(acc[m][p][q * 4 + 2]);
        o.w = f2bf(acc[m][p][q * 4 + 3]);
        *(ushort4*)(out + obase + (size_t)px * 64 + ocb) = o;
      }
    }
#pragma unroll
    for (int r = 0; r < 16; ++r) {
      const float a0 = acc[m][0][r], a1 = acc[m][1][r];
      sv[m][r] = a0 + a1;
      qv[m][r] = a0 * a0 + a1 * a1;
    }
  }
#pragma unroll
  for (int st = 1; st <= 16; st <<= 1)
#pragma unroll
    for (int m = 0; m < 2; ++m)
#pragma unroll
      for (int r = 0; r < 16; ++r) {
        sv[m][r] += __shfl_xor(sv[m][r], st);
        qv[m][r] += __shfl_xor(qv[m][r], st);
      }
  if (l31 == 0) {
#pragma unroll
    for (int m = 0; m < 2; ++m)
#pragma unroll
      for (int r = 0; r < 16; ++r) {
        const int oc = m * 32 + (r & 3) + 8 * (r >> 2) + 4 * hi;
        s_red[0][wv][oc] = sv[m][r];
        s_red[1][wv][oc] = qv[m][r];
      }
  }
  __syncthreads();
  if (t < 64) {
    psum[(size_t)t * NPB + b] = s_red[0][0][t] + s_red[0][1][t] +
                                s_red[0][2][t] + s_red[0][3][t];
    psq [(size_t)t * NPB + b] = s_red[1][0][t] + s_red[1][1][t] +
                                s_red[1][2][t] + s_red[1][3][t];
  }
}

// ---- MFMA implicit-GEMM 3x3 conv 64->64, v8: weights in REGISTERS.
// wf[9][4][2] (288 VGPR) loaded once from linear global (L2-hot); one-time
// loads drain at k=0's vmcnt(0), so counted vmcnt(16) stays exact after.
// LDS = A-ring only (84.5 KB): compute phase = 2 ds_read per 4 MFMA.
// __launch_bounds__(256,1): true occupancy is 1 wave/SIMD -> 512-VGPR budget.
__global__ __launch_bounds__(256, 1)
void k_mconv(const unsigned short* __restrict__ in,
             const unsigned short* __restrict__ wt,
             unsigned short* __restrict__ out,
             float* __restrict__ psum, float* __restrict__ psq) {
  __shared__ __align__(16) unsigned short ring[10 * 528 * 8]; // 84.48 KB
  __shared__ float s_red[2][4][64];                           // 2 KB

  const int t = threadIdx.x;
  const int lane = t & 63, wv = t >> 6;   // wave = row-in-tile (0..3)
  const int l31 = lane & 31, hi = lane >> 5;
  const int bo = blockIdx.x;
  const int b = (bo & 7) * 64 + (bo >> 3);  // XCD swizzle (512 = 8*64)
  const int n  = b >> 6;
  const int hb = (b >> 2) & 15;             // 16-row band
  const int w0 = (b & 3) * 64;

  // ---- W fragments -> registers, once (linear layout: [tap][oc][ic])
  bfx8 wf[9][4][2];
#pragma unroll
  for (int tap = 0; tap < 9; ++tap)
#pragma unroll
    for (int ks = 0; ks < 4; ++ks)
#pragma unroll
      for (int m = 0; m < 2; ++m)
        wf[tap][ks][m] = *(const bfx8*)(wt + (size_t)tap * 4096 +
                          (size_t)(m * 32 + l31) * 64 + ks * 16 + hi * 8);

  // prologue: logical rows 0..5 -> slots 0..5 (3168 chunks)
  {
    const size_t gb = ((size_t)n * 258 + hb * 16) * 258 + w0;
#pragma unroll
    for (int j = 0; j < 13; ++j) {
      const int id = t + j * 256;
      if (id < 3168) {
        const int r = id / 528, c = id - r * 528;
        const int px = c >> 3;
        const int R = r * 66 + px;
        const int sl = (c & 7) ^ (R & 7);
        gload16(in + (gb + (size_t)r * 258 + px) * 64 + sl * 8,
                ring + (size_t)id * 8);
      }
    }
  }

  float sv[2][16] = {{0.f}}, qv[2][16] = {{0.f}};

  for (int k = 0; k < 4; ++k) {
    if (k == 0) { asm volatile("s_waitcnt vmcnt(0)" ::: "memory"); }
    else       { asm volatile("s_waitcnt vmcnt(16)" ::: "memory"); }
    __builtin_amdgcn_sched_barrier(0);
    __builtin_amdgcn_s_barrier();
    __builtin_amdgcn_sched_barrier(0);
    if (k < 3) {  // stage rows 4k+6..4k+9 for tile k+1
      const int base = 4 * k + 6;
#pragma unroll
      for (int j = 0; j < 9; ++j) {
        const int id = t + j * 256;
        if (id < 2112) {
          const int r = id / 528, c = id - r * 528;
          const int Lr = base + r;
          const int s = (Lr >= 10) ? Lr - 10 : Lr;
          const int px = c >> 3;
          const int R = s * 66 + px;
          const int sl = (c & 7) ^ (R & 7);
          gload16(in + (((size_t)n * 258 + hb * 16 + Lr) * 258 + w0 + px) * 64 + sl * 8,
                  ring + ((size_t)s * 528 + c) * 8);
        }
      }
    }
    __builtin_amdgcn_sched_barrier(0);

    fx16 acc[2][2] = {};
#pragma unroll
    for (int tap = 0; tap < 9; ++tap) {
      const int dh = tap / 3, dw = tap - dh * 3;
      const int Lr = 4 * k + wv + dh;
      const int s = (Lr >= 10) ? Lr - 10 : Lr;
      const int Rbase = s * 66 + dw;
#pragma unroll
      for (int ks = 0; ks < 4; ++ks) {
        bfx8 bf[2];
#pragma unroll
        for (int p = 0; p < 2; ++p) {
          const int R = Rbase + p * 32 + l31;
          const int slA = (ks * 2 + hi) ^ (R & 7);
          bf[p] = *(const bfx8*)((const char*)ring + (size_t)R * 128 + (slA << 4));
        }
#pragma unroll
        for (int m = 0; m < 2; ++m)
#pragma unroll
          for (int p = 0; p < 2; ++p)
            acc[m][p] = __builtin_amdgcn_mfma_f32_32x32x16_bf16(
                wf[tap][ks][m], bf[p], acc[m][p], 0, 0, 0);
      }
    }

    const int orow = hb * 16 + 4 * k + wv + 1;
    const size_t obase = (((size_t)n * 258 + orow) * 258 + (w0 + 1)) * 64;
#pragma unroll
    for (int m = 0; m < 2; ++m) {
#pragma unroll
      for (int p = 0; p < 2; ++p) {
        const int px = p * 32 + l31;
#pragma unroll
        for (int q = 0; q < 4; ++q) {
          const int ocb = m * 32 + q * 8 + 4 * hi;
          ushort4 o;
          o.x = f2bf(acc[m][p][q * 4 + 0]);
          o.y = f2bf(acc[m][p][q * 4 + 1]);
          o.z = f2bf(acc[m][p][q * 4 + 2]);
          o.w = f2bf(acc[m][p][q * 4 + 3]);
          *(ushort4*)(out + obase + (size_t)px * 64 + ocb) = o;
        }
      }
#pragma unroll
      for (int r = 0; r < 16; ++r) {
        const float a0 = acc[m][0][r], a1 = acc[m][1][r];
        sv[m][r] += a0 + a1;
        qv[m][r] += a0 * a0 + a1 * a1;
      }
    }
  }

  // stats epilogue: butterfly + cross-wave LDS reduce
#pragma unroll
  for (int st = 1; st <= 16; st <<= 1)
#pragma unroll
    for (int m = 0; m < 2; ++m)
#pragma unroll
      for (int r = 0; r < 16; ++r) {
        sv[m][r] += __shfl_xor(sv[m][r], st);
        qv[m][r] += __shfl_xor(qv[m][r], st);
      }
  if (l31 == 0) {
#pragma unroll
    for (int m = 0; m < 2; ++m)
#pragma unroll
      for (int r = 0; r < 16; ++r) {
        const int oc = m * 32 + (r & 3) + 8 * (r >> 2) + 4 * hi;
        s_red[0][wv][oc] = sv[m][r];
        s_red[1][wv][oc] = qv[m][r];
      }
  }
  __syncthreads();
  if (t < 64) {
    psum[(size_t)t * NPB + bo] = s_red[0][0][t] + s_red[0][1][t] +
                                 s_red[0][2][t] + s_red[0][3][t];
    psq [(size_t)t * NPB + bo] = s_red[1][0][t] + s_red[1][1][t] +
                                 s_red[1][2][t] + s_red[1][3][t];
  }
}

// ---- BN stats finalize: one block per channel, coalesced partial reduce
__global__ __launch_bounds__(256)
void k_bnfin(const float* __restrict__ psum, const float* __restrict__ psq,
             const float* __restrict__ g, const float* __restrict__ be,
             float* __restrict__ bnp, int nb) {
  __shared__ float s1[256], s2[256];
  const int c = blockIdx.x;
  const int t = threadIdx.x;
  float s = 0.f, q = 0.f;
  for (int j = t; j < nb; j += 256) {
    s += psum[(size_t)c * NPB + j];
    q += psq[(size_t)c * NPB + j];
  }
  s1[t] = s; s2[t] = q;
  __syncthreads();
  for (int st = 128; st > 0; st >>= 1) {
    if (t < st) { s1[t] += s1[t + st]; s2[t] += s2[t + st]; }
    __syncthreads();
  }
  if (t == 0) {
    const float m = s1[0] / PTOTF;
    const float var = s2[0] / PTOTF - m * m;
    const float sc = g[c] * rsqrtf(var + 1e-5f);
    bnp[c] = sc;
    bnp[64 + c] = be[c] - m * sc;
  }
}

// ---- elementwise: RES=0: a = celu(bn(y));  RES=1: a += celu(bn(y))
template<int RES>
__global__ __launch_bounds__(256)
void k_apply(const unsigned short* __restrict__ y, const float* __restrict__ bnp,
             unsigned short* __restrict__ a) {
  const size_t gid = (size_t)blockIdx.x * 256 + threadIdx.x;
  const int px = (int)(gid >> 3);
  const int c0 = ((int)gid & 7) * 8;
  const int n = px >> 16, hh = (px >> 8) & 255, ww = px & 255;
  const size_t i = padpx(n, hh, ww) * 64 + c0;
  float v[8];
  unpack8(*(const uint4*)(y + i), v);
  const float4 sa = *(const float4*)(bnp + c0);
  const float4 sb = *(const float4*)(bnp + c0 + 4);
  const float4 ha = *(const float4*)(bnp + 64 + c0);
  const float4 hb = *(const float4*)(bnp + 64 + c0 + 4);
  const float sc[8] = {sa.x, sa.y, sa.z, sa.w, sb.x, sb.y, sb.z, sb.w};
  const float sh[8] = {ha.x, ha.y, ha.z, ha.w, hb.x, hb.y, hb.z, hb.w};
  float r[8];
#pragma unroll
  for (int q = 0; q < 8; ++q) r[q] = celuf(v[q] * sc[q] + sh[q]);
  if (RES) {
    float av[8];
    unpack8(*(const uint4*)(a + i), av);
#pragma unroll
    for (int q = 0; q < 8; ++q) r[q] += av[q];
  }
  uint4 o;
  o.x = (unsigned)f2bf(r[0]) | ((unsigned)f2bf(r[1]) << 16);
  o.y = (unsigned)f2bf(r[2]) | ((unsigned)f2bf(r[3]) << 16);
  o.z = (unsigned)f2bf(r[4]) | ((unsigned)f2bf(r[5]) << 16);
  o.w = (unsigned)f2bf(r[6]) | ((unsigned)f2bf(r[7]) << 16);
  *(uint4*)(a + i) = o;
}

// ---- last conv 64->3 via MFMA 16x16x32 (validated round 16)
__global__ __launch_bounds__(256, 2)
void k_last(const unsigned short* __restrict__ a, const float* __restrict__ x,
            const unsigned short* __restrict__ wl, const float* __restrict__ b2,
            float* __restrict__ outp) {
  __shared__ __align__(16) unsigned short a_s[3168 * 8];  // 50688 B

  const int t = threadIdx.x;
  const int lane = t & 63, wv = t >> 6;
  int b = blockIdx.x;
  b = (b & 7) * 256 + (b >> 3);  // XCD swizzle
  const int n  = b >> 8;
  const int h0 = ((b >> 2) & 63) * 4;
  const int w0 = (b & 3) * 64;

  const size_t ibase = ((size_t)n * 258 + h0) * 258 + w0;
  for (int seg = wv; seg < 54; seg += 4) {
    const int r = seg / 9;
    const int p = seg - r * 9;
    const int c = p * 64 + lane;
    const int px = c >> 3;
    const int R = r * 66 + px;
    const int sl = (c & 7) ^ (R & 7);
    if (c < 528)
      gload16(a + (ibase + (size_t)r * 258 + px) * 64 + sl * 8,
              a_s + (size_t)(r * 528 + p * 64) * 8);
  }
  __syncthreads();

  const int col = lane & 15, kg = lane >> 4;
  const float bz0 = b2[0], bz1 = b2[1], bz2 = b2[2];
#pragma unroll
  for (int ti = 0; ti < 4; ++ti) {
    fx4 acc = {};
#pragma unroll
    for (int tap = 0; tap < 9; ++tap) {
      const int dh = tap / 3, dw = tap - dh * 3;
      const int px = ti * 16 + col + dw;
      const int R = (wv + dh) * 66 + px;
#pragma unroll
      for (int kc = 0; kc < 2; ++kc) {
        const int s = kc * 4 + kg;
        const bfx8 bf = *(const bfx8*)((const char*)a_s +
            (size_t)R * 128 + ((s ^ (R & 7)) << 4));
        const bfx8 af = *(const bfx8*)(wl + ((size_t)(tap * 2 + kc) * 64 + lane) * 8);
        acc = __builtin_amdgcn_mfma_f32_16x16x32_bf16(af, bf, acc, 0, 0, 0);
      }
    }
    if (kg == 0) {
      const int h = h0 + wv;
      const size_t ob = (size_t)n * 3 * HW + ((size_t)h << 8) + w0 + ti * 16 + col;
      outp[ob]          = celuf(acc[0] + bz0) + x[ob];
      outp[ob + HW]     = celuf(acc[1] + bz1) + x[ob + HW];
      outp[ob + 2 * HW] = celuf(acc[2] + bz2) + x[ob + 2 * HW];
    }
  }
}

extern "C" void kernel_launch(void* const* d_in, const int* in_sizes, int n_in,
                              void* d_out, int out_size, void* d_ws, size_t ws_size,
                              hipStream_t stream) {
  const float* x   = (const float*)d_in[0];
  const float* w1  = (const float*)d_in[1];
  // d_in[2] = b1 (cancels under BN)
  const float* g1  = (const float*)d_in[3];
  const float* be1 = (const float*)d_in[4];
  const float* bw  = (const float*)d_in[5];
  // d_in[6] = bb (cancels under BN)
  const float* bg  = (const float*)d_in[7];
  const float* bbe = (const float*)d_in[8];
  const float* w2  = (const float*)d_in[9];
  const float* b2  = (const float*)d_in[10];
  float* out = (float*)d_out;

  const size_t PADBUF = (size_t)8 * 258 * 258 * 64 * 2;  // bytes
  size_t off = 0;
  auto alloc = [&](size_t bytes) {
    size_t cur = off;
    off += (bytes + 255) & ~(size_t)255;
    return cur;
  };
  const size_t oA   = alloc(PADBUF);
  const size_t oB   = alloc(PADBUF);
  const size_t oC   = alloc(PADBUF);
  const size_t oW1  = alloc(5120 * 2);               // wc1 bf16 frag table
  const size_t oWM  = alloc((size_t)6 * 36864 * 2);  // bf16 linear
  const size_t oWL  = alloc(9216 * 2);               // wlast bf16 frag table
  const size_t oMS  = alloc(48 * 4);
  const size_t oBNP = alloc(7 * 128 * 4);
  const size_t oPS  = alloc((size_t)64 * NPB * 4);
  const size_t oPQ  = alloc((size_t)64 * NPB * 4);
  if (off > ws_size) return;

  char* wsb = (char*)d_ws;
  unsigned short* bufA = (unsigned short*)(wsb + oA);
  unsigned short* bufB = (unsigned short*)(wsb + oB);
  unsigned short* bufC = (unsigned short*)(wsb + oC);
  unsigned short* wc1 = (unsigned short*)(wsb + oW1);
  unsigned short* wtm = (unsigned short*)(wsb + oWM);
  unsigned short* wlast = (unsigned short*)(wsb + oWL);
  float* ms  = (float*)(wsb + oMS);
  float* bnp = (float*)(wsb + oBNP);
  float* psum = (float*)(wsb + oPS);
  float* psq  = (float*)(wsb + oPQ);

  k_prep<<<1017, 256, 0, stream>>>(w1, bw, w2, wc1, wtm, wlast, bufA, bufB, bufC);
  k_inorm<<<24, 256, 0, stream>>>(x, ms);

  // conv1 (6->64) MFMA -> raw bufB + fused stats; act0 -> bufA
  k_conv1<<<2048, 256, 0, stream>>>(x, ms, wc1, bufB, psum, psq);
  k_bnfin<<<64, 256, 0, stream>>>(psum, psq, g1, be1, bnp, 2048);
  k_apply<0><<<16384, 256, 0, stream>>>(bufB, bnp, bufA);

  for (int i = 0; i < 3; ++i) {
    const int s1 = 1 + 2 * i, s2 = 2 + 2 * i;
    // conv A (act) -> B raw (+fused stats)
    k_mconv<<<512, 256, 0, stream>>>(bufA, wtm + (size_t)(2 * i) * 36864,
                                     bufB, psum, psq);
    k_bnfin<<<64, 256, 0, stream>>>(psum, psq, bg + (size_t)(2 * i) * 64,
        bbe + (size_t)(2 * i) * 64, bnp + (size_t)s1 * 128, 512);
    // act mid -> C
    k_apply<0><<<16384, 256, 0, stream>>>(bufB, bnp + (size_t)s1 * 128, bufC);
    // conv C (act) -> B raw (+fused stats)
    k_mconv<<<512, 256, 0, stream>>>(bufC, wtm + (size_t)(2 * i + 1) * 36864,
                                     bufB, psum, psq);
    k_bnfin<<<64, 256, 0, stream>>>(psum, psq, bg + (size_t)(2 * i + 1) * 64,
        bbe + (size_t)(2 * i + 1) * 64, bnp + (size_t)s2 * 128, 512);
    // residual: A += celu(bn(B))
    k_apply<1><<<16384, 256, 0, stream>>>(bufB, bnp + (size_t)s2 * 128, bufA);
  }

  k_last<<<2048, 256, 0, stream>>>(bufA, x, wlast, b2, out);
}

// Round 22
// 790.569 us; speedup vs baseline: 1.1702x; 1.1702x over previous
//
#include <hip/hip_runtime.h>
#include <cstdint>
#include <cstddef>

#define DEVI __device__ __forceinline__

static constexpr int HW = 65536;          // 256*256
static constexpr float PTOTF = 524288.0f; // 8*256*256
static constexpr int NPB = 8192;          // partial-stats stride (max blocks)

typedef __attribute__((ext_vector_type(8))) short bfx8;
typedef __attribute__((ext_vector_type(16))) float fx16;
typedef __attribute__((ext_vector_type(4))) float fx4;

DEVI unsigned short f2bf(float f) {
  unsigned int x = __float_as_uint(f);
  x += 0x7fffu + ((x >> 16) & 1u);
  return (unsigned short)(x >> 16);
}
DEVI float celuf(float v) { return v > 0.0f ? v : expm1f(v); }

DEVI void unpack8(const uint4 u, float* v) {
  v[0] = __uint_as_float(u.x << 16); v[1] = __uint_as_float(u.x & 0xffff0000u);
  v[2] = __uint_as_float(u.y << 16); v[3] = __uint_as_float(u.y & 0xffff0000u);
  v[4] = __uint_as_float(u.z << 16); v[5] = __uint_as_float(u.z & 0xffff0000u);
  v[6] = __uint_as_float(u.w << 16); v[7] = __uint_as_float(u.w & 0xffff0000u);
}

// async 16B global->LDS (linear LDS dest = uniform base + lane*16)
DEVI void gload16(const unsigned short* g, unsigned short* l) {
  __builtin_amdgcn_global_load_lds(
      (const __attribute__((address_space(1))) unsigned int*)g,
      (__attribute__((address_space(3))) unsigned int*)l, 16, 0, 0);
}

// padded pixel base index: interior (n,h,w) -> element offset/64
DEVI size_t padpx(int n, int h, int w) {
  return ((size_t)n * 258 + (h + 1)) * 258 + (w + 1);
}

// ---- merged prep: pad-zero borders + weight transforms
// wtm: LINEAR [cv][9 taps][64 oc][64 ic] bf16 (consumed via registers).
// wc1: conv1 A-frag table [5 kchunks][2 oc-halves][64 lanes][8].
// wlast: bf16 A-fragment table [18 chunks][64 lanes][8] for mfma 16x16x32.
__global__ __launch_bounds__(256)
void k_prep(const float* __restrict__ w1, const float* __restrict__ bw,
            const float* __restrict__ w2, unsigned short* __restrict__ wc1,
            unsigned short* __restrict__ wtm, unsigned short* __restrict__ wlast,
            unsigned short* a, unsigned short* b, unsigned short* c) {
  int id = blockIdx.x * 256 + threadIdx.x;
  if (id < 24672) {  // pad-zero: 3 bufs x 8 n x 1028 border px
    const int buf = id / 8224, r = id - buf * 8224;
    const int n = r / 1028, k = r - n * 1028;
    int hp, wp;
    if (k < 258)      { hp = 0;           wp = k; }
    else if (k < 516) { hp = 257;         wp = k - 258; }
    else if (k < 772) { hp = k - 516 + 1; wp = 0; }
    else              { hp = k - 772 + 1; wp = 257; }
    unsigned short* p = (buf == 0 ? a : buf == 1 ? b : c) +
                        (((size_t)n * 258 + hp) * 258 + wp) * 64;
    const uint4 z = {0, 0, 0, 0};
#pragma unroll
    for (int q = 0; q < 8; ++q) ((uint4*)p)[q] = z;
    return;
  }
  id -= 24672;
  if (id < 221184) {  // wtm: bw [6][64][64][3][3] f32 -> [6][9][64][64] bf16
    const int cv = id / 36864, r = id - cv * 36864;
    const int tap = r >> 12, rr = r & 4095, oc = rr >> 6, ic = rr & 63;
    const float v = bw[((size_t)cv * 4096 + oc * 64 + ic) * 9 + tap];
    wtm[(size_t)cv * 36864 + tap * 4096 + oc * 64 + ic] = f2bf(v);
    return;
  }
  id -= 221184;
  if (id < 5120) {  // wc1 table
    const int cch = id >> 10, rr = id & 1023;
    const int m = rr >> 9, l = (rr >> 3) & 63, j = rr & 7;
    const int oc = m * 32 + (l & 31);
    const int tap = 2 * cch + (l >> 5);
    wc1[id] = (tap < 9 && j < 6) ? f2bf(w1[(oc * 6 + j) * 9 + tap])
                                 : (unsigned short)0;
    return;
  }
  id -= 5120;
  if (id < 9216) {  // wlast bf16 table
    const int cch = id >> 9, r = id & 511, l = r >> 3, j = r & 7;
    const int oc = l & 15, kg = l >> 4;
    const int tap = cch >> 1, kc = cch & 1;
    const int ic = kc * 32 + kg * 8 + j;
    wlast[id] = (oc < 3) ? f2bf(w2[(oc * 64 + ic) * 9 + tap]) : (unsigned short)0;
  }
}

// ---- instance norm stats: one block per (n,c)
__global__ __launch_bounds__(256)
void k_inorm(const float* __restrict__ x, float* __restrict__ ms) {
  __shared__ float s1[256], s2[256];
  const int b = blockIdx.x;
  const float4* p = (const float4*)(x + (size_t)b * HW);
  float sum = 0.f, sq = 0.f;
  for (int j = threadIdx.x; j < HW / 4; j += 256) {
    const float4 v = p[j];
    sum += v.x + v.y + v.z + v.w;
    sq  += v.x * v.x + v.y * v.y + v.z * v.z + v.w * v.w;
  }
  s1[threadIdx.x] = sum; s2[threadIdx.x] = sq;
  __syncthreads();
  for (int s = 128; s > 0; s >>= 1) {
    if ((int)threadIdx.x < s) {
      s1[threadIdx.x] += s1[threadIdx.x + s];
      s2[threadIdx.x] += s2[threadIdx.x + s];
    }
    __syncthreads();
  }
  if (threadIdx.x == 0) {
    const float m = s1[0] * (1.0f / HW);
    const float var = (s2[0] - s1[0] * s1[0] * (1.0f / HW)) * (1.0f / (HW - 1));
    ms[2 * b] = m;
    ms[2 * b + 1] = rsqrtf(var);
  }
}

// ---- conv1 (6->64) via MFMA (validated round 20): tile 4 rows x 64 px x 64 oc.
__global__ __launch_bounds__(256)
void k_conv1(const float* __restrict__ x, const float* __restrict__ ms,
             const unsigned short* __restrict__ wc1, unsigned short* __restrict__ out,
             float* __restrict__ psum, float* __restrict__ psq) {
  __shared__ __align__(16) unsigned short in_s[6 * 66 * 8];  // 6336 B
  __shared__ float s_red[2][4][64];

  const int t = threadIdx.x;
  const int lane = t & 63, wv = t >> 6;
  const int l31 = lane & 31, hi = lane >> 5;
  const int b = blockIdx.x;
  const int n = b >> 8;
  const int h0 = ((b >> 2) & 63) * 4;
  const int w0 = (b & 3) * 64;

  const float m0 = ms[6 * n + 0], r0 = ms[6 * n + 1];
  const float m1 = ms[6 * n + 2], r1 = ms[6 * n + 3];
  const float m2 = ms[6 * n + 4], r2 = ms[6 * n + 5];

  for (int id = t; id < 396; id += 256) {
    const int r = id / 66, px = id - r * 66;
    const int gh = h0 + r - 1, gw = w0 + px - 1;
    uint4 u = {0, 0, 0, 0};
    if (((unsigned)gh < 256u) && ((unsigned)gw < 256u)) {
      const float* xp = x + (size_t)n * 3 * HW + gh * 256 + gw;
      const float a0 = xp[0], a1 = xp[HW], a2 = xp[2 * HW];
      const float n0 = (a0 - m0) * r0, n1 = (a1 - m1) * r1, n2 = (a2 - m2) * r2;
      u.x = (unsigned)f2bf(a0) | ((unsigned)f2bf(a1) << 16);
      u.y = (unsigned)f2bf(a2) | ((unsigned)f2bf(n0) << 16);
      u.z = (unsigned)f2bf(n1) | ((unsigned)f2bf(n2) << 16);
    }
    *(uint4*)(in_s + (size_t)id * 8) = u;
  }
  __syncthreads();

  fx16 acc[2][2] = {};
#pragma unroll
  for (int c = 0; c < 5; ++c) {
    bfx8 af[2];
#pragma unroll
    for (int m = 0; m < 2; ++m)
      af[m] = *(const bfx8*)(wc1 + ((size_t)(c * 2 + m) * 64 + lane) * 8);
    const int tap = 2 * c + hi;
    const int dh = (tap < 9) ? tap / 3 : 0;
    const int dw = (tap < 9) ? (tap - (tap / 3) * 3) : 0;
    bfx8 bf[2];
#pragma unroll
    for (int p = 0; p < 2; ++p) {
      const int px = p * 32 + l31 + dw;
      bf[p] = *(const bfx8*)(in_s + ((size_t)(wv + dh) * 66 + px) * 8);
    }
#pragma unroll
    for (int m = 0; m < 2; ++m)
#pragma unroll
      for (int p = 0; p < 2; ++p)
        acc[m][p] = __builtin_amdgcn_mfma_f32_32x32x16_bf16(
            af[m], bf[p], acc[m][p], 0, 0, 0);
  }

  const size_t obase = (((size_t)n * 258 + (h0 + wv + 1)) * 258 + (w0 + 1)) * 64;
  float sv[2][16], qv[2][16];
#pragma unroll
  for (int m = 0; m < 2; ++m) {
#pragma unroll
    for (int p = 0; p < 2; ++p) {
      const int px = p * 32 + l31;
#pragma unroll
      for (int q = 0; q < 4; ++q) {
        const int ocb = m * 32 + q * 8 + 4 * hi;
        ushort4 o;
        o.x = f2bf(acc[m][p][q * 4 + 0]);
        o.y = f2bf(acc[m][p][q * 4 + 1]);
        o.z = f2bf(acc[m][p][q * 4 + 2]);
        o.w = f2bf(acc[m][p][q * 4 + 3]);
        *(ushort4*)(out + obase + (size_t)px * 64 + ocb) = o;
      }
    }
#pragma unroll
    for (int r = 0; r < 16; ++r) {
      const float a0 = acc[m][0][r], a1 = acc[m][1][r];
      sv[m][r] = a0 + a1;
      qv[m][r] = a0 * a0 + a1 * a1;
    }
  }
#pragma unroll
  for (int st = 1; st <= 16; st <<= 1)
#pragma unroll
    for (int m = 0; m < 2; ++m)
#pragma unroll
      for (int r = 0; r < 16; ++r) {
        sv[m][r] += __shfl_xor(sv[m][r], st);
        qv[m][r] += __shfl_xor(qv[m][r], st);
      }
  if (l31 == 0) {
#pragma unroll
    for (int m = 0; m < 2; ++m)
#pragma unroll
      for (int r = 0; r < 16; ++r) {
        const int oc = m * 32 + (r & 3) + 8 * (r >> 2) + 4 * hi;
        s_red[0][wv][oc] = sv[m][r];
        s_red[1][wv][oc] = qv[m][r];
      }
  }
  __syncthreads();
  if (t < 64) {
    psum[(size_t)t * NPB + b] = s_red[0][0][t] + s_red[0][1][t] +
                                s_red[0][2][t] + s_red[0][3][t];
    psq [(size_t)t * NPB + b] = s_red[1][0][t] + s_red[1][1][t] +
                                s_red[1][2][t] + s_red[1][3][t];
  }
}

// ---- MFMA implicit-GEMM 3x3 conv 64->64, v9: 512 thr / 8 waves,
// wave = (row, oc-half m). wf[9][4] = 144 VGPR per wave (fits 256 cap:
// live set ~230). bf reads 1 per MFMA; no weight LDS reads; 8 waves/CU.
// Counted vmcnt(8): 8 stores/thread are newest; older stage loads retired.
__global__ __launch_bounds__(512, 2)
void k_mconv(const unsigned short* __restrict__ in,
             const unsigned short* __restrict__ wt,
             unsigned short* __restrict__ out,
             float* __restrict__ psum, float* __restrict__ psq) {
  __shared__ __align__(16) unsigned short ring[10 * 528 * 8]; // 84.48 KB
  __shared__ float s_red[2][8][64];                           // 4 KB

  const int t = threadIdx.x;
  const int lane = t & 63, wv = t >> 6;   // 8 waves
  const int l31 = lane & 31, hi = lane >> 5;
  const int row = wv >> 1;                // 0..3 row-in-tile
  const int m   = wv & 1;                 // oc half
  const int bo = blockIdx.x;
  const int b = (bo & 7) * 64 + (bo >> 3);  // XCD swizzle (512 = 8*64)
  const int n  = b >> 6;
  const int hb = (b >> 2) & 15;             // 16-row band
  const int w0 = (b & 3) * 64;

  // ---- this wave's W fragments -> registers (linear [tap][oc][ic])
  bfx8 wf[9][4];
#pragma unroll
  for (int tap = 0; tap < 9; ++tap)
#pragma unroll
    for (int ks = 0; ks < 4; ++ks)
      wf[tap][ks] = *(const bfx8*)(wt + (size_t)tap * 4096 +
                      (size_t)(m * 32 + l31) * 64 + ks * 16 + hi * 8);

  // prologue: logical rows 0..5 -> slots 0..5 (3168 chunks)
  {
    const size_t gb = ((size_t)n * 258 + hb * 16) * 258 + w0;
#pragma unroll
    for (int j = 0; j < 7; ++j) {
      const int id = t + j * 512;
      if (id < 3168) {
        const int r = id / 528, c = id - r * 528;
        const int px = c >> 3;
        const int R = r * 66 + px;
        const int sl = (c & 7) ^ (R & 7);
        gload16(in + (gb + (size_t)r * 258 + px) * 64 + sl * 8,
                ring + (size_t)id * 8);
      }
    }
  }

  float sv[16] = {0.f}, qv[16] = {0.f};

  for (int k = 0; k < 4; ++k) {
    if (k == 0) { asm volatile("s_waitcnt vmcnt(0)" ::: "memory"); }
    else       { asm volatile("s_waitcnt vmcnt(8)" ::: "memory"); }
    __builtin_amdgcn_sched_barrier(0);
    __builtin_amdgcn_s_barrier();
    __builtin_amdgcn_sched_barrier(0);
    if (k < 3) {  // stage rows 4k+6..4k+9 for tile k+1 (disjoint slots)
      const int base = 4 * k + 6;
#pragma unroll
      for (int j = 0; j < 5; ++j) {
        const int id = t + j * 512;
        if (id < 2112) {
          const int r = id / 528, c = id - r * 528;
          const int Lr = base + r;
          const int s = (Lr >= 10) ? Lr - 10 : Lr;
          const int px = c >> 3;
          const int R = s * 66 + px;
          const int sl = (c & 7) ^ (R & 7);
          gload16(in + (((size_t)n * 258 + hb * 16 + Lr) * 258 + w0 + px) * 64 + sl * 8,
                  ring + ((size_t)s * 528 + c) * 8);
        }
      }
    }
    __builtin_amdgcn_sched_barrier(0);

    fx16 acc[2] = {};
#pragma unroll
    for (int tap = 0; tap < 9; ++tap) {
      const int dh = tap / 3, dw = tap - dh * 3;
      const int Lr = 4 * k + row + dh;
      const int s = (Lr >= 10) ? Lr - 10 : Lr;
      const int Rbase = s * 66 + dw;
#pragma unroll
      for (int ks = 0; ks < 4; ++ks) {
        bfx8 bf[2];
#pragma unroll
        for (int p = 0; p < 2; ++p) {
          const int R = Rbase + p * 32 + l31;
          const int slA = (ks * 2 + hi) ^ (R & 7);
          bf[p] = *(const bfx8*)((const char*)ring + (size_t)R * 128 + (slA << 4));
        }
#pragma unroll
        for (int p = 0; p < 2; ++p)
          acc[p] = __builtin_amdgcn_mfma_f32_32x32x16_bf16(
              wf[tap][ks], bf[p], acc[p], 0, 0, 0);
      }
    }

    const int orow = hb * 16 + 4 * k + row + 1;
    const size_t obase = (((size_t)n * 258 + orow) * 258 + (w0 + 1)) * 64;
#pragma unroll
    for (int p = 0; p < 2; ++p) {
      const int px = p * 32 + l31;
#pragma unroll
      for (int q = 0; q < 4; ++q) {
        const int ocb = m * 32 + q * 8 + 4 * hi;
        ushort4 o;
        o.x = f2bf(acc[p][q * 4 + 0]);
        o.y = f2bf(acc[p][q * 4 + 1]);
        o.z = f2bf(acc[p][q * 4 + 2]);
        o.w = f2bf(acc[p][q * 4 + 3]);
        *(ushort4*)(out + obase + (size_t)px * 64 + ocb) = o;
      }
    }
#pragma unroll
    for (int r = 0; r < 16; ++r) {
      const float a0 = acc[0][r], a1 = acc[1][r];
      sv[r] += a0 + a1;
      qv[r] += a0 * a0 + a1 * a1;
    }
  }

  // stats epilogue: butterfly + cross-wave LDS reduce (wave owns 32 oc)
#pragma unroll
  for (int st = 1; st <= 16; st <<= 1)
#pragma unroll
    for (int r = 0; r < 16; ++r) {
      sv[r] += __shfl_xor(sv[r], st);
      qv[r] += __shfl_xor(qv[r], st);
    }
  if (l31 == 0) {
#pragma unroll
    for (int r = 0; r < 16; ++r) {
      const int oc = m * 32 + (r & 3) + 8 * (r >> 2) + 4 * hi;
      s_red[0][wv][oc] = sv[r];
      s_red[1][wv][oc] = qv[r];
    }
  }
  __syncthreads();
  if (t < 64) {
    const int mm = t >> 5;  // which oc-half this channel belongs to
    psum[(size_t)t * NPB + bo] = s_red[0][0 * 2 + mm][t] + s_red[0][1 * 2 + mm][t] +
                                 s_red[0][2 * 2 + mm][t] + s_red[0][3 * 2 + mm][t];
    psq [(size_t)t * NPB + bo] = s_red[1][0 * 2 + mm][t] + s_red[1][1 * 2 + mm][t] +
                                 s_red[1][2 * 2 + mm][t] + s_red[1][3 * 2 + mm][t];
  }
}

// ---- BN stats finalize: one block per channel, coalesced partial reduce
__global__ __launch_bounds__(256)
void k_bnfin(const float* __restrict__ psum, const float* __restrict__ psq,
             const float* __restrict__ g, const float* __restrict__ be,
             float* __restrict__ bnp, int nb) {
  __shared__ float s1[256], s2[256];
  const int c = blockIdx.x;
  const int t = threadIdx.x;
  float s = 0.f, q = 0.f;
  for (int j = t; j < nb; j += 256) {
    s += psum[(size_t)c * NPB + j];
    q += psq[(size_t)c * NPB + j];
  }
  s1[t] = s; s2[t] = q;
  __syncthreads();
  for (int st = 128; st > 0; st >>= 1) {
    if (t < st) { s1[t] += s1[t + st]; s2[t] += s2[t + st]; }
    __syncthreads();
  }
  if (t == 0) {
    const float m = s1[0] / PTOTF;
    const float var = s2[0] / PTOTF - m * m;
    const float sc = g[c] * rsqrtf(var + 1e-5f);
    bnp[c] = sc;
    bnp[64 + c] = be[c] - m * sc;
  }
}

// ---- elementwise: RES=0: a = celu(bn(y));  RES=1: a += celu(bn(y))
template<int RES>
__global__ __launch_bounds__(256)
void k_apply(const unsigned short* __restrict__ y, const float* __restrict__ bnp,
             unsigned short* __restrict__ a) {
  const size_t gid = (size_t)blockIdx.x * 256 + threadIdx.x;
  const int px = (int)(gid >> 3);
  const int c0 = ((int)gid & 7) * 8;
  const int n = px >> 16, hh = (px >> 8) & 255, ww = px & 255;
  const size_t i = padpx(n, hh, ww) * 64 + c0;
  float v[8];
  unpack8(*(const uint4*)(y + i), v);
  const float4 sa = *(const float4*)(bnp + c0);
  const float4 sb = *(const float4*)(bnp + c0 + 4);
  const float4 ha = *(const float4*)(bnp + 64 + c0);
  const float4 hb = *(const float4*)(bnp + 64 + c0 + 4);
  const float sc[8] = {sa.x, sa.y, sa.z, sa.w, sb.x, sb.y, sb.z, sb.w};
  const float sh[8] = {ha.x, ha.y, ha.z, ha.w, hb.x, hb.y, hb.z, hb.w};
  float r[8];
#pragma unroll
  for (int q = 0; q < 8; ++q) r[q] = celuf(v[q] * sc[q] + sh[q]);
  if (RES) {
    float av[8];
    unpack8(*(const uint4*)(a + i), av);
#pragma unroll
    for (int q = 0; q < 8; ++q) r[q] += av[q];
  }
  uint4 o;
  o.x = (unsigned)f2bf(r[0]) | ((unsigned)f2bf(r[1]) << 16);
  o.y = (unsigned)f2bf(r[2]) | ((unsigned)f2bf(r[3]) << 16);
  o.z = (unsigned)f2bf(r[4]) | ((unsigned)f2bf(r[5]) << 16);
  o.w = (unsigned)f2bf(r[6]) | ((unsigned)f2bf(r[7]) << 16);
  *(uint4*)(a + i) = o;
}

// ---- last conv 64->3 via MFMA 16x16x32 (validated round 16)
__global__ __launch_bounds__(256, 2)
void k_last(const unsigned short* __restrict__ a, const float* __restrict__ x,
            const unsigned short* __restrict__ wl, const float* __restrict__ b2,
            float* __restrict__ outp) {
  __shared__ __align__(16) unsigned short a_s[3168 * 8];  // 50688 B

  const int t = threadIdx.x;
  const int lane = t & 63, wv = t >> 6;
  int b = blockIdx.x;
  b = (b & 7) * 256 + (b >> 3);  // XCD swizzle
  const int n  = b >> 8;
  const int h0 = ((b >> 2) & 63) * 4;
  const int w0 = (b & 3) * 64;

  const size_t ibase = ((size_t)n * 258 + h0) * 258 + w0;
  for (int seg = wv; seg < 54; seg += 4) {
    const int r = seg / 9;
    const int p = seg - r * 9;
    const int c = p * 64 + lane;
    const int px = c >> 3;
    const int R = r * 66 + px;
    const int sl = (c & 7) ^ (R & 7);
    if (c < 528)
      gload16(a + (ibase + (size_t)r * 258 + px) * 64 + sl * 8,
              a_s + (size_t)(r * 528 + p * 64) * 8);
  }
  __syncthreads();

  const int col = lane & 15, kg = lane >> 4;
  const float bz0 = b2[0], bz1 = b2[1], bz2 = b2[2];
#pragma unroll
  for (int ti = 0; ti < 4; ++ti) {
    fx4 acc = {};
#pragma unroll
    for (int tap = 0; tap < 9; ++tap) {
      const int dh = tap / 3, dw = tap - dh * 3;
      const int px = ti * 16 + col + dw;
      const int R = (wv + dh) * 66 + px;
#pragma unroll
      for (int kc = 0; kc < 2; ++kc) {
        const int s = kc * 4 + kg;
        const bfx8 bf = *(const bfx8*)((const char*)a_s +
            (size_t)R * 128 + ((s ^ (R & 7)) << 4));
        const bfx8 af = *(const bfx8*)(wl + ((size_t)(tap * 2 + kc) * 64 + lane) * 8);
        acc = __builtin_amdgcn_mfma_f32_16x16x32_bf16(af, bf, acc, 0, 0, 0);
      }
    }
    if (kg == 0) {
      const int h = h0 + wv;
      const size_t ob = (size_t)n * 3 * HW + ((size_t)h << 8) + w0 + ti * 16 + col;
      outp[ob]          = celuf(acc[0] + bz0) + x[ob];
      outp[ob + HW]     = celuf(acc[1] + bz1) + x[ob + HW];
      outp[ob + 2 * HW] = celuf(acc[2] + bz2) + x[ob + 2 * HW];
    }
  }
}

extern "C" void kernel_launch(void* const* d_in, const int* in_sizes, int n_in,
                              void* d_out, int out_size, void* d_ws, size_t ws_size,
                              hipStream_t stream) {
  const float* x   = (const float*)d_in[0];
  const float* w1  = (const float*)d_in[1];
  // d_in[2] = b1 (cancels under BN)
  const float* g1  = (const float*)d_in[3];
  const float* be1 = (const float*)d_in[4];
  const float* bw  = (const float*)d_in[5];
  // d_in[6] = bb (cancels under BN)
  const float* bg  = (const float*)d_in[7];
  const float* bbe = (const float*)d_in[8];
  const float* w2  = (const float*)d_in[9];
  const float* b2  = (const float*)d_in[10];
  float* out = (float*)d_out;

  const size_t PADBUF = (size_t)8 * 258 * 258 * 64 * 2;  // bytes
  size_t off = 0;
  auto alloc = [&](size_t bytes) {
    size_t cur = off;
    off += (bytes + 255) & ~(size_t)255;
    return cur;
  };
  const size_t oA   = alloc(PADBUF);
  const size_t oB   = alloc(PADBUF);
  const size_t oC   = alloc(PADBUF);
  const size_t oW1  = alloc(5120 * 2);               // wc1 bf16 frag table
  const size_t oWM  = alloc((size_t)6 * 36864 * 2);  // bf16 linear
  const size_t oWL  = alloc(9216 * 2);               // wlast bf16 frag table
  const size_t oMS  = alloc(48 * 4);
  const size_t oBNP = alloc(7 * 128 * 4);
  const size_t oPS  = alloc((size_t)64 * NPB * 4);
  const size_t oPQ  = alloc((size_t)64 * NPB * 4);
  if (off > ws_size) return;

  char* wsb = (char*)d_ws;
  unsigned short* bufA = (unsigned short*)(wsb + oA);
  unsigned short* bufB = (unsigned short*)(wsb + oB);
  unsigned short* bufC = (unsigned short*)(wsb + oC);
  unsigned short* wc1 = (unsigned short*)(wsb + oW1);
  unsigned short* wtm = (unsigned short*)(wsb + oWM);
  unsigned short* wlast = (unsigned short*)(wsb + oWL);
  float* ms  = (float*)(wsb + oMS);
  float* bnp = (float*)(wsb + oBNP);
  float* psum = (float*)(wsb + oPS);
  float* psq  = (float*)(wsb + oPQ);

  k_prep<<<1017, 256, 0, stream>>>(w1, bw, w2, wc1, wtm, wlast, bufA, bufB, bufC);
  k_inorm<<<24, 256, 0, stream>>>(x, ms);

  // conv1 (6->64) MFMA -> raw bufB + fused stats; act0 -> bufA
  k_conv1<<<2048, 256, 0, stream>>>(x, ms, wc1, bufB, psum, psq);
  k_bnfin<<<64, 256, 0, stream>>>(psum, psq, g1, be1, bnp, 2048);
  k_apply<0><<<16384, 256, 0, stream>>>(bufB, bnp, bufA);

  for (int i = 0; i < 3; ++i) {
    const int s1 = 1 + 2 * i, s2 = 2 + 2 * i;
    // conv A (act) -> B raw (+fused stats)
    k_mconv<<<512, 512, 0, stream>>>(bufA, wtm + (size_t)(2 * i) * 36864,
                                     bufB, psum, psq);
    k_bnfin<<<64, 256, 0, stream>>>(psum, psq, bg + (size_t)(2 * i) * 64,
        bbe + (size_t)(2 * i) * 64, bnp + (size_t)s1 * 128, 512);
    // act mid -> C
    k_apply<0><<<16384, 256, 0, stream>>>(bufB, bnp + (size_t)s1 * 128, bufC);
    // conv C (act) -> B raw (+fused stats)
    k_mconv<<<512, 512, 0, stream>>>(bufC, wtm + (size_t)(2 * i + 1) * 36864,
                                     bufB, psum, psq);
    k_bnfin<<<64, 256, 0, stream>>>(psum, psq, bg + (size_t)(2 * i + 1) * 64,
        bbe + (size_t)(2 * i + 1) * 64, bnp + (size_t)s2 * 128, 512);
    // residual: A += celu(bn(B))
    k_apply<1><<<16384, 256, 0, stream>>>(bufB, bnp + (size_t)s2 * 128, bufA);
  }

  k_last<<<2048, 256, 0, stream>>>(bufA, x, wlast, b2, out);
}

// Round 23
// 676.032 us; speedup vs baseline: 1.3684x; 1.1694x over previous
//
#include <hip/hip_runtime.h>
#include <cstdint>
#include <cstddef>

#define DEVI __device__ __forceinline__

static constexpr int HW = 65536;          // 256*256
static constexpr float PTOTF = 524288.0f; // 8*256*256
static constexpr int NPB = 8192;          // partial-stats stride (max blocks)

typedef __attribute__((ext_vector_type(8))) short bfx8;
typedef __attribute__((ext_vector_type(16))) float fx16;
typedef __attribute__((ext_vector_type(4))) float fx4;

DEVI unsigned short f2bf(float f) {
  unsigned int x = __float_as_uint(f);
  x += 0x7fffu + ((x >> 16) & 1u);
  return (unsigned short)(x >> 16);
}
DEVI float celuf(float v) { return v > 0.0f ? v : expm1f(v); }

DEVI void unpack8(const uint4 u, float* v) {
  v[0] = __uint_as_float(u.x << 16); v[1] = __uint_as_float(u.x & 0xffff0000u);
  v[2] = __uint_as_float(u.y << 16); v[3] = __uint_as_float(u.y & 0xffff0000u);
  v[4] = __uint_as_float(u.z << 16); v[5] = __uint_as_float(u.z & 0xffff0000u);
  v[6] = __uint_as_float(u.w << 16); v[7] = __uint_as_float(u.w & 0xffff0000u);
}

// async 16B global->LDS (linear LDS dest = uniform base + lane*16)
DEVI void gload16(const unsigned short* g, unsigned short* l) {
  __builtin_amdgcn_global_load_lds(
      (const __attribute__((address_space(1))) unsigned int*)g,
      (__attribute__((address_space(3))) unsigned int*)l, 16, 0, 0);
}

// padded pixel base index: interior (n,h,w) -> element offset/64
DEVI size_t padpx(int n, int h, int w) {
  return ((size_t)n * 258 + (h + 1)) * 258 + (w + 1);
}

// ---- merged prep: pad-zero borders + weight transforms
// wtm: ic-slice XOR-swizzled (dst slice s holds src slice s^(oc&7)) for
// linear gload16 -> conflict-free swizzled ds_reads (validated r16-r20).
// wc1: conv1 A-frag table [5 kchunks][2 oc-halves][64 lanes][8].
// wlast: bf16 A-fragment table [18 chunks][64 lanes][8] for mfma 16x16x32.
__global__ __launch_bounds__(256)
void k_prep(const float* __restrict__ w1, const float* __restrict__ bw,
            const float* __restrict__ w2, unsigned short* __restrict__ wc1,
            unsigned short* __restrict__ wtm, unsigned short* __restrict__ wlast,
            unsigned short* a, unsigned short* b, unsigned short* c) {
  int id = blockIdx.x * 256 + threadIdx.x;
  if (id < 24672) {  // pad-zero: 3 bufs x 8 n x 1028 border px
    const int buf = id / 8224, r = id - buf * 8224;
    const int n = r / 1028, k = r - n * 1028;
    int hp, wp;
    if (k < 258)      { hp = 0;           wp = k; }
    else if (k < 516) { hp = 257;         wp = k - 258; }
    else if (k < 772) { hp = k - 516 + 1; wp = 0; }
    else              { hp = k - 772 + 1; wp = 257; }
    unsigned short* p = (buf == 0 ? a : buf == 1 ? b : c) +
                        (((size_t)n * 258 + hp) * 258 + wp) * 64;
    const uint4 z = {0, 0, 0, 0};
#pragma unroll
    for (int q = 0; q < 8; ++q) ((uint4*)p)[q] = z;
    return;
  }
  id -= 24672;
  if (id < 221184) {  // wtm: bw [6][64][64][3][3] f32 -> [6][9][64][64] bf16 swz
    const int cv = id / 36864, r = id - cv * 36864;
    const int tap = r >> 12, rr = r & 4095, oc = rr >> 6, ic = rr & 63;
    const float v = bw[((size_t)cv * 4096 + oc * 64 + ic) * 9 + tap];
    const int dic = ((((ic >> 3) ^ (oc & 7)) << 3) | (ic & 7));
    wtm[(size_t)cv * 36864 + tap * 4096 + oc * 64 + dic] = f2bf(v);
    return;
  }
  id -= 221184;
  if (id < 5120) {  // wc1 table
    const int cch = id >> 10, rr = id & 1023;
    const int m = rr >> 9, l = (rr >> 3) & 63, j = rr & 7;
    const int oc = m * 32 + (l & 31);
    const int tap = 2 * cch + (l >> 5);
    wc1[id] = (tap < 9 && j < 6) ? f2bf(w1[(oc * 6 + j) * 9 + tap])
                                 : (unsigned short)0;
    return;
  }
  id -= 5120;
  if (id < 9216) {  // wlast bf16 table
    const int cch = id >> 9, r = id & 511, l = r >> 3, j = r & 7;
    const int oc = l & 15, kg = l >> 4;
    const int tap = cch >> 1, kc = cch & 1;
    const int ic = kc * 32 + kg * 8 + j;
    wlast[id] = (oc < 3) ? f2bf(w2[(oc * 64 + ic) * 9 + tap]) : (unsigned short)0;
  }
}

// ---- instance norm stats: one block per (n,c)
__global__ __launch_bounds__(256)
void k_inorm(const float* __restrict__ x, float* __restrict__ ms) {
  __shared__ float s1[256], s2[256];
  const int b = blockIdx.x;
  const float4* p = (const float4*)(x + (size_t)b * HW);
  float sum = 0.f, sq = 0.f;
  for (int j = threadIdx.x; j < HW / 4; j += 256) {
    const float4 v = p[j];
    sum += v.x + v.y + v.z + v.w;
    sq  += v.x * v.x + v.y * v.y + v.z * v.z + v.w * v.w;
  }
  s1[threadIdx.x] = sum; s2[threadIdx.x] = sq;
  __syncthreads();
  for (int s = 128; s > 0; s >>= 1) {
    if ((int)threadIdx.x < s) {
      s1[threadIdx.x] += s1[threadIdx.x + s];
      s2[threadIdx.x] += s2[threadIdx.x + s];
    }
    __syncthreads();
  }
  if (threadIdx.x == 0) {
    const float m = s1[0] * (1.0f / HW);
    const float var = (s2[0] - s1[0] * s1[0] * (1.0f / HW)) * (1.0f / (HW - 1));
    ms[2 * b] = m;
    ms[2 * b + 1] = rsqrtf(var);
  }
}

// ---- conv1 (6->64) via MFMA (validated round 20): tile 4 rows x 64 px x 64 oc.
__global__ __launch_bounds__(256)
void k_conv1(const float* __restrict__ x, const float* __restrict__ ms,
             const unsigned short* __restrict__ wc1, unsigned short* __restrict__ out,
             float* __restrict__ psum, float* __restrict__ psq) {
  __shared__ __align__(16) unsigned short in_s[6 * 66 * 8];  // 6336 B
  __shared__ float s_red[2][4][64];

  const int t = threadIdx.x;
  const int lane = t & 63, wv = t >> 6;
  const int l31 = lane & 31, hi = lane >> 5;
  const int b = blockIdx.x;
  const int n = b >> 8;
  const int h0 = ((b >> 2) & 63) * 4;
  const int w0 = (b & 3) * 64;

  const float m0 = ms[6 * n + 0], r0 = ms[6 * n + 1];
  const float m1 = ms[6 * n + 2], r1 = ms[6 * n + 3];
  const float m2 = ms[6 * n + 4], r2 = ms[6 * n + 5];

  for (int id = t; id < 396; id += 256) {
    const int r = id / 66, px = id - r * 66;
    const int gh = h0 + r - 1, gw = w0 + px - 1;
    uint4 u = {0, 0, 0, 0};
    if (((unsigned)gh < 256u) && ((unsigned)gw < 256u)) {
      const float* xp = x + (size_t)n * 3 * HW + gh * 256 + gw;
      const float a0 = xp[0], a1 = xp[HW], a2 = xp[2 * HW];
      const float n0 = (a0 - m0) * r0, n1 = (a1 - m1) * r1, n2 = (a2 - m2) * r2;
      u.x = (unsigned)f2bf(a0) | ((unsigned)f2bf(a1) << 16);
      u.y = (unsigned)f2bf(a2) | ((unsigned)f2bf(n0) << 16);
      u.z = (unsigned)f2bf(n1) | ((unsigned)f2bf(n2) << 16);
    }
    *(uint4*)(in_s + (size_t)id * 8) = u;
  }
  __syncthreads();

  fx16 acc[2][2] = {};
#pragma unroll
  for (int c = 0; c < 5; ++c) {
    bfx8 af[2];
#pragma unroll
    for (int m = 0; m < 2; ++m)
      af[m] = *(const bfx8*)(wc1 + ((size_t)(c * 2 + m) * 64 + lane) * 8);
    const int tap = 2 * c + hi;
    const int dh = (tap < 9) ? tap / 3 : 0;
    const int dw = (tap < 9) ? (tap - (tap / 3) * 3) : 0;
    bfx8 bf[2];
#pragma unroll
    for (int p = 0; p < 2; ++p) {
      const int px = p * 32 + l31 + dw;
      bf[p] = *(const bfx8*)(in_s + ((size_t)(wv + dh) * 66 + px) * 8);
    }
#pragma unroll
    for (int m = 0; m < 2; ++m)
#pragma unroll
      for (int p = 0; p < 2; ++p)
        acc[m][p] = __builtin_amdgcn_mfma_f32_32x32x16_bf16(
            af[m], bf[p], acc[m][p], 0, 0, 0);
  }

  const size_t obase = (((size_t)n * 258 + (h0 + wv + 1)) * 258 + (w0 + 1)) * 64;
  float sv[2][16], qv[2][16];
#pragma unroll
  for (int m = 0; m < 2; ++m) {
#pragma unroll
    for (int p = 0; p < 2; ++p) {
      const int px = p * 32 + l31;
#pragma unroll
      for (int q = 0; q < 4; ++q) {
        const int ocb = m * 32 + q * 8 + 4 * hi;
        ushort4 o;
        o.x = f2bf(acc[m][p][q * 4 + 0]);
        o.y = f2bf(acc[m][p][q * 4 + 1]);
        o.z = f2bf(acc[m][p][q * 4 + 2]);
        o.w = f2bf(acc[m][p][q * 4 + 3]);
        *(ushort4*)(out + obase + (size_t)px * 64 + ocb) = o;
      }
    }
#pragma unroll
    for (int r = 0; r < 16; ++r) {
      const float a0 = acc[m][0][r], a1 = acc[m][1][r];
      sv[m][r] = a0 + a1;
      qv[m][r] = a0 * a0 + a1 * a1;
    }
  }
#pragma unroll
  for (int st = 1; st <= 16; st <<= 1)
#pragma unroll
    for (int m = 0; m < 2; ++m)
#pragma unroll
      for (int r = 0; r < 16; ++r) {
        sv[m][r] += __shfl_xor(sv[m][r], st);
        qv[m][r] += __shfl_xor(qv[m][r], st);
      }
  if (l31 == 0) {
#pragma unroll
    for (int m = 0; m < 2; ++m)
#pragma unroll
      for (int r = 0; r < 16; ++r) {
        const int oc = m * 32 + (r & 3) + 8 * (r >> 2) + 4 * hi;
        s_red[0][wv][oc] = sv[m][r];
        s_red[1][wv][oc] = qv[m][r];
      }
  }
  __syncthreads();
  if (t < 64) {
    psum[(size_t)t * NPB + b] = s_red[0][0][t] + s_red[0][1][t] +
                                s_red[0][2][t] + s_red[0][3][t];
    psq [(size_t)t * NPB + b] = s_red[1][0][t] + s_red[1][1][t] +
                                s_red[1][2][t] + s_red[1][3][t];
  }
}

// ---- MFMA implicit-GEMM 3x3 conv 64->64, v10: v7 LDS path + 8 waves.
// 512 thr / 8 waves; wave = (row, oc-half m): 2 waves/SIMD hides ds_read
// latency (v7's 1 wave/SIMD could not). Per (tap,ks): 1 wf + 2 bf reads
// feed 2 MFMAs. Live set ~100 VGPR < 128 cap -> no spill. W in LDS (72KB,
// swizzled), A in 10-slot ring (84.5KB), s_red 4KB = 158.5 KB total.
// vmcnt(8): 8 stores/thread newest; older stage loads retired in-order.
__global__ __launch_bounds__(512, 2)
void k_mconv(const unsigned short* __restrict__ in,
             const unsigned short* __restrict__ wt,
             unsigned short* __restrict__ out,
             float* __restrict__ psum, float* __restrict__ psq) {
  __shared__ __align__(16) unsigned short w_s[36864];         // 72 KB
  __shared__ __align__(16) unsigned short ring[10 * 528 * 8]; // 84.48 KB
  __shared__ float s_red[2][8][64];                           // 4 KB

  const int t = threadIdx.x;
  const int lane = t & 63, wv = t >> 6;   // 8 waves
  const int l31 = lane & 31, hi = lane >> 5;
  const int row = wv >> 1;                // 0..3 row-in-tile
  const int m   = wv & 1;                 // oc half
  const int bo = blockIdx.x;
  const int b = (bo & 7) * 64 + (bo >> 3);  // XCD swizzle (512 = 8*64)
  const int n  = b >> 6;
  const int hb = (b >> 2) & 15;             // 16-row band
  const int w0 = (b & 3) * 64;
  const int oc = m * 32 + l31;

  // stage all weights: 4608 chunks, 9/thread (linear; global pre-swizzled)
#pragma unroll
  for (int j = 0; j < 9; ++j) {
    const int id = t + j * 512;
    gload16(wt + (size_t)id * 8, w_s + (size_t)id * 8);
  }
  // prologue: logical rows 0..5 -> slots 0..5 (3168 chunks)
  {
    const size_t gb = ((size_t)n * 258 + hb * 16) * 258 + w0;
#pragma unroll
    for (int j = 0; j < 7; ++j) {
      const int id = t + j * 512;
      if (id < 3168) {
        const int r = id / 528, c = id - r * 528;
        const int px = c >> 3;
        const int R = r * 66 + px;
        const int sl = (c & 7) ^ (R & 7);
        gload16(in + (gb + (size_t)r * 258 + px) * 64 + sl * 8,
                ring + (size_t)id * 8);
      }
    }
  }

  float sv[16] = {0.f}, qv[16] = {0.f};

  for (int k = 0; k < 4; ++k) {
    if (k == 0) { asm volatile("s_waitcnt vmcnt(0)" ::: "memory"); }
    else       { asm volatile("s_waitcnt vmcnt(8)" ::: "memory"); }
    __builtin_amdgcn_sched_barrier(0);
    __builtin_amdgcn_s_barrier();
    __builtin_amdgcn_sched_barrier(0);
    if (k < 3) {  // stage rows 4k+6..4k+9 for tile k+1 (disjoint slots)
      const int base = 4 * k + 6;
#pragma unroll
      for (int j = 0; j < 5; ++j) {
        const int id = t + j * 512;
        if (id < 2112) {
          const int r = id / 528, c = id - r * 528;
          const int Lr = base + r;
          const int s = (Lr >= 10) ? Lr - 10 : Lr;
          const int px = c >> 3;
          const int R = s * 66 + px;
          const int sl = (c & 7) ^ (R & 7);
          gload16(in + (((size_t)n * 258 + hb * 16 + Lr) * 258 + w0 + px) * 64 + sl * 8,
                  ring + ((size_t)s * 528 + c) * 8);
        }
      }
    }
    __builtin_amdgcn_sched_barrier(0);

    fx16 acc[2] = {};
#pragma unroll
    for (int tap = 0; tap < 9; ++tap) {
      const int dh = tap / 3, dw = tap - dh * 3;
      const int Lr = 4 * k + row + dh;
      const int s = (Lr >= 10) ? Lr - 10 : Lr;
      const int Rbase = s * 66 + dw;
#pragma unroll
      for (int ks = 0; ks < 4; ++ks) {
        const int slW = (ks * 2 + hi) ^ (oc & 7);
        const bfx8 wf = *(const bfx8*)((const char*)w_s +
                         ((size_t)tap * 4096 + oc * 64) * 2 + (slW << 4));
        bfx8 bf[2];
#pragma unroll
        for (int p = 0; p < 2; ++p) {
          const int R = Rbase + p * 32 + l31;
          const int slA = (ks * 2 + hi) ^ (R & 7);
          bf[p] = *(const bfx8*)((const char*)ring + (size_t)R * 128 + (slA << 4));
        }
#pragma unroll
        for (int p = 0; p < 2; ++p)
          acc[p] = __builtin_amdgcn_mfma_f32_32x32x16_bf16(
              wf, bf[p], acc[p], 0, 0, 0);
      }
    }

    const int orow = hb * 16 + 4 * k + row + 1;
    const size_t obase = (((size_t)n * 258 + orow) * 258 + (w0 + 1)) * 64;
#pragma unroll
    for (int p = 0; p < 2; ++p) {
      const int px = p * 32 + l31;
#pragma unroll
      for (int q = 0; q < 4; ++q) {
        const int ocb = m * 32 + q * 8 + 4 * hi;
        ushort4 o;
        o.x = f2bf(acc[p][q * 4 + 0]);
        o.y = f2bf(acc[p][q * 4 + 1]);
        o.z = f2bf(acc[p][q * 4 + 2]);
        o.w = f2bf(acc[p][q * 4 + 3]);
        *(ushort4*)(out + obase + (size_t)px * 64 + ocb) = o;
      }
    }
#pragma unroll
    for (int r = 0; r < 16; ++r) {
      const float a0 = acc[0][r], a1 = acc[1][r];
      sv[r] += a0 + a1;
      qv[r] += a0 * a0 + a1 * a1;
    }
  }

  // stats epilogue: butterfly + cross-wave LDS reduce (wave owns 32 oc)
#pragma unroll
  for (int st = 1; st <= 16; st <<= 1)
#pragma unroll
    for (int r = 0; r < 16; ++r) {
      sv[r] += __shfl_xor(sv[r], st);
      qv[r] += __shfl_xor(qv[r], st);
    }
  if (l31 == 0) {
#pragma unroll
    for (int r = 0; r < 16; ++r) {
      const int oc2 = m * 32 + (r & 3) + 8 * (r >> 2) + 4 * hi;
      s_red[0][wv][oc2] = sv[r];
      s_red[1][wv][oc2] = qv[r];
    }
  }
  __syncthreads();
  if (t < 64) {
    const int mm = t >> 5;  // which oc-half this channel belongs to
    psum[(size_t)t * NPB + bo] = s_red[0][0 * 2 + mm][t] + s_red[0][1 * 2 + mm][t] +
                                 s_red[0][2 * 2 + mm][t] + s_red[0][3 * 2 + mm][t];
    psq [(size_t)t * NPB + bo] = s_red[1][0 * 2 + mm][t] + s_red[1][1 * 2 + mm][t] +
                                 s_red[1][2 * 2 + mm][t] + s_red[1][3 * 2 + mm][t];
  }
}

// ---- BN stats finalize: one block per channel, coalesced partial reduce
__global__ __launch_bounds__(256)
void k_bnfin(const float* __restrict__ psum, const float* __restrict__ psq,
             const float* __restrict__ g, const float* __restrict__ be,
             float* __restrict__ bnp, int nb) {
  __shared__ float s1[256], s2[256];
  const int c = blockIdx.x;
  const int t = threadIdx.x;
  float s = 0.f, q = 0.f;
  for (int j = t; j < nb; j += 256) {
    s += psum[(size_t)c * NPB + j];
    q += psq[(size_t)c * NPB + j];
  }
  s1[t] = s; s2[t] = q;
  __syncthreads();
  for (int st = 128; st > 0; st >>= 1) {
    if (t < st) { s1[t] += s1[t + st]; s2[t] += s2[t + st]; }
    __syncthreads();
  }
  if (t == 0) {
    const float m = s1[0] / PTOTF;
    const float var = s2[0] / PTOTF - m * m;
    const float sc = g[c] * rsqrtf(var + 1e-5f);
    bnp[c] = sc;
    bnp[64 + c] = be[c] - m * sc;
  }
}

// ---- elementwise: RES=0: a = celu(bn(y));  RES=1: a += celu(bn(y))
template<int RES>
__global__ __launch_bounds__(256)
void k_apply(const unsigned short* __restrict__ y, const float* __restrict__ bnp,
             unsigned short* __restrict__ a) {
  const size_t gid = (size_t)blockIdx.x * 256 + threadIdx.x;
  const int px = (int)(gid >> 3);
  const int c0 = ((int)gid & 7) * 8;
  const int n = px >> 16, hh = (px >> 8) & 255, ww = px & 255;
  const size_t i = padpx(n, hh, ww) * 64 + c0;
  float v[8];
  unpack8(*(const uint4*)(y + i), v);
  const float4 sa = *(const float4*)(bnp + c0);
  const float4 sb = *(const float4*)(bnp + c0 + 4);
  const float4 ha = *(const float4*)(bnp + 64 + c0);
  const float4 hb = *(const float4*)(bnp + 64 + c0 + 4);
  const float sc[8] = {sa.x, sa.y, sa.z, sa.w, sb.x, sb.y, sb.z, sb.w};
  const float sh[8] = {ha.x, ha.y, ha.z, ha.w, hb.x, hb.y, hb.z, hb.w};
  float r[8];
#pragma unroll
  for (int q = 0; q < 8; ++q) r[q] = celuf(v[q] * sc[q] + sh[q]);
  if (RES) {
    float av[8];
    unpack8(*(const uint4*)(a + i), av);
#pragma unroll
    for (int q = 0; q < 8; ++q) r[q] += av[q];
  }
  uint4 o;
  o.x = (unsigned)f2bf(r[0]) | ((unsigned)f2bf(r[1]) << 16);
  o.y = (unsigned)f2bf(r[2]) | ((unsigned)f2bf(r[3]) << 16);
  o.z = (unsigned)f2bf(r[4]) | ((unsigned)f2bf(r[5]) << 16);
  o.w = (unsigned)f2bf(r[6]) | ((unsigned)f2bf(r[7]) << 16);
  *(uint4*)(a + i) = o;
}

// ---- last conv 64->3 via MFMA 16x16x32 (validated round 16)
__global__ __launch_bounds__(256, 2)
void k_last(const unsigned short* __restrict__ a, const float* __restrict__ x,
            const unsigned short* __restrict__ wl, const float* __restrict__ b2,
            float* __restrict__ outp) {
  __shared__ __align__(16) unsigned short a_s[3168 * 8];  // 50688 B

  const int t = threadIdx.x;
  const int lane = t & 63, wv = t >> 6;
  int b = blockIdx.x;
  b = (b & 7) * 256 + (b >> 3);  // XCD swizzle
  const int n  = b >> 8;
  const int h0 = ((b >> 2) & 63) * 4;
  const int w0 = (b & 3) * 64;

  const size_t ibase = ((size_t)n * 258 + h0) * 258 + w0;
  for (int seg = wv; seg < 54; seg += 4) {
    const int r = seg / 9;
    const int p = seg - r * 9;
    const int c = p * 64 + lane;
    const int px = c >> 3;
    const int R = r * 66 + px;
    const int sl = (c & 7) ^ (R & 7);
    if (c < 528)
      gload16(a + (ibase + (size_t)r * 258 + px) * 64 + sl * 8,
              a_s + (size_t)(r * 528 + p * 64) * 8);
  }
  __syncthreads();

  const int col = lane & 15, kg = lane >> 4;
  const float bz0 = b2[0], bz1 = b2[1], bz2 = b2[2];
#pragma unroll
  for (int ti = 0; ti < 4; ++ti) {
    fx4 acc = {};
#pragma unroll
    for (int tap = 0; tap < 9; ++tap) {
      const int dh = tap / 3, dw = tap - dh * 3;
      const int px = ti * 16 + col + dw;
      const int R = (wv + dh) * 66 + px;
#pragma unroll
      for (int kc = 0; kc < 2; ++kc) {
        const int s = kc * 4 + kg;
        const bfx8 bf = *(const bfx8*)((const char*)a_s +
            (size_t)R * 128 + ((s ^ (R & 7)) << 4));
        const bfx8 af = *(const bfx8*)(wl + ((size_t)(tap * 2 + kc) * 64 + lane) * 8);
        acc = __builtin_amdgcn_mfma_f32_16x16x32_bf16(af, bf, acc, 0, 0, 0);
      }
    }
    if (kg == 0) {
      const int h = h0 + wv;
      const size_t ob = (size_t)n * 3 * HW + ((size_t)h << 8) + w0 + ti * 16 + col;
      outp[ob]          = celuf(acc[0] + bz0) + x[ob];
      outp[ob + HW]     = celuf(acc[1] + bz1) + x[ob + HW];
      outp[ob + 2 * HW] = celuf(acc[2] + bz2) + x[ob + 2 * HW];
    }
  }
}

extern "C" void kernel_launch(void* const* d_in, const int* in_sizes, int n_in,
                              void* d_out, int out_size, void* d_ws, size_t ws_size,
                              hipStream_t stream) {
  const float* x   = (const float*)d_in[0];
  const float* w1  = (const float*)d_in[1];
  // d_in[2] = b1 (cancels under BN)
  const float* g1  = (const float*)d_in[3];
  const float* be1 = (const float*)d_in[4];
  const float* bw  = (const float*)d_in[5];
  // d_in[6] = bb (cancels under BN)
  const float* bg  = (const float*)d_in[7];
  const float* bbe = (const float*)d_in[8];
  const float* w2  = (const float*)d_in[9];
  const float* b2  = (const float*)d_in[10];
  float* out = (float*)d_out;

  const size_t PADBUF = (size_t)8 * 258 * 258 * 64 * 2;  // bytes
  size_t off = 0;
  auto alloc = [&](size_t bytes) {
    size_t cur = off;
    off += (bytes + 255) & ~(size_t)255;
    return cur;
  };
  const size_t oA   = alloc(PADBUF);
  const size_t oB   = alloc(PADBUF);
  const size_t oC   = alloc(PADBUF);
  const size_t oW1  = alloc(5120 * 2);               // wc1 bf16 frag table
  const size_t oWM  = alloc((size_t)6 * 36864 * 2);  // bf16 swizzled
  const size_t oWL  = alloc(9216 * 2);               // wlast bf16 frag table
  const size_t oMS  = alloc(48 * 4);
  const size_t oBNP = alloc(7 * 128 * 4);
  const size_t oPS  = alloc((size_t)64 * NPB * 4);
  const size_t oPQ  = alloc((size_t)64 * NPB * 4);
  if (off > ws_size) return;

  char* wsb = (char*)d_ws;
  unsigned short* bufA = (unsigned short*)(wsb + oA);
  unsigned short* bufB = (unsigned short*)(wsb + oB);
  unsigned short* bufC = (unsigned short*)(wsb + oC);
  unsigned short* wc1 = (unsigned short*)(wsb + oW1);
  unsigned short* wtm = (unsigned short*)(wsb + oWM);
  unsigned short* wlast = (unsigned short*)(wsb + oWL);
  float* ms  = (float*)(wsb + oMS);
  float* bnp = (float*)(wsb + oBNP);
  float* psum = (float*)(wsb + oPS);
  float* psq  = (float*)(wsb + oPQ);

  k_prep<<<1017, 256, 0, stream>>>(w1, bw, w2, wc1, wtm, wlast, bufA, bufB, bufC);
  k_inorm<<<24, 256, 0, stream>>>(x, ms);

  // conv1 (6->64) MFMA -> raw bufB + fused stats; act0 -> bufA
  k_conv1<<<2048, 256, 0, stream>>>(x, ms, wc1, bufB, psum, psq);
  k_bnfin<<<64, 256, 0, stream>>>(psum, psq, g1, be1, bnp, 2048);
  k_apply<0><<<16384, 256, 0, stream>>>(bufB, bnp, bufA);

  for (int i = 0; i < 3; ++i) {
    const int s1 = 1 + 2 * i, s2 = 2 + 2 * i;
    // conv A (act) -> B raw (+fused stats)
    k_mconv<<<512, 512, 0, stream>>>(bufA, wtm + (size_t)(2 * i) * 36864,
                                     bufB, psum, psq);
    k_bnfin<<<64, 256, 0, stream>>>(psum, psq, bg + (size_t)(2 * i) * 64,
        bbe + (size_t)(2 * i) * 64, bnp + (size_t)s1 * 128, 512);
    // act mid -> C
    k_apply<0><<<16384, 256, 0, stream>>>(bufB, bnp + (size_t)s1 * 128, bufC);
    // conv C (act) -> B raw (+fused stats)
    k_mconv<<<512, 512, 0, stream>>>(bufC, wtm + (size_t)(2 * i + 1) * 36864,
                                     bufB, psum, psq);
    k_bnfin<<<64, 256, 0, stream>>>(psum, psq, bg + (size_t)(2 * i + 1) * 64,
        bbe + (size_t)(2 * i + 1) * 64, bnp + (size_t)s2 * 128, 512);
    // residual: A += celu(bn(B))
    k_apply<1><<<16384, 256, 0, stream>>>(bufB, bnp + (size_t)s2 * 128, bufA);
  }

  k_last<<<2048, 256, 0, stream>>>(bufA, x, wlast, b2, out);
}